// Round 5
// baseline (110.816 us; speedup 1.0000x reference)
//
#include <hip/hip_runtime.h>
#include <stdint.h>

#define SEQ 4096
#define FDIM 128
#define NH 4
#define HD 32
#define NB 2
#define NROWS (NB * NH * SEQ)  // 32768
#define LOG2E 1.4426950408889634f
#define VCOL 72            // shorts per Vp column (36 dwords)
#define VHALF (32 * VCOL)  // shorts per Vp buffer (4608 B)

typedef float f32x4 __attribute__((ext_vector_type(4)));
typedef __bf16 bf16x8 __attribute__((ext_vector_type(8)));

__device__ __forceinline__ unsigned short f2bf(float f) {
  unsigned int u = __builtin_bit_cast(unsigned int, f);
  return (unsigned short)((u + 0x7FFFu + ((u >> 16) & 1u)) >> 16);  // RTNE
}

// ---- pre-pass 1: fp32 -> bf16 ----
__global__ void cvt_kernel(const float* __restrict__ in, unsigned short* __restrict__ out) {
  int i = (blockIdx.x * 256 + threadIdx.x) * 4;
  float4 v = *reinterpret_cast<const float4*>(in + i);
  ushort4 o;
  o.x = f2bf(v.x); o.y = f2bf(v.y); o.z = f2bf(v.z); o.w = f2bf(v.w);
  *reinterpret_cast<ushort4*>(out + i) = o;
}

// ---- pre-pass 2: adjacency int32 -> bitmask; 16 ints/thread ----
__global__ void adjpack_kernel(const int* __restrict__ adj, unsigned short* __restrict__ bits16) {
  size_t t = (size_t)blockIdx.x * 256 + threadIdx.x;
  const uint4* p = reinterpret_cast<const uint4*>(adj) + t * 4;
  uint4 a = p[0], b = p[1], c = p[2], d = p[3];
  unsigned m = 0;
  m |= (a.x != 0) ? 1u : 0u;        m |= (a.y != 0) ? 2u : 0u;
  m |= (a.z != 0) ? 4u : 0u;        m |= (a.w != 0) ? 8u : 0u;
  m |= (b.x != 0) ? 16u : 0u;       m |= (b.y != 0) ? 32u : 0u;
  m |= (b.z != 0) ? 64u : 0u;       m |= (b.w != 0) ? 128u : 0u;
  m |= (c.x != 0) ? 256u : 0u;      m |= (c.y != 0) ? 512u : 0u;
  m |= (c.z != 0) ? 1024u : 0u;     m |= (c.w != 0) ? 2048u : 0u;
  m |= (d.x != 0) ? 4096u : 0u;     m |= (d.y != 0) ? 8192u : 0u;
  m |= (d.z != 0) ? 16384u : 0u;    m |= (d.w != 0) ? 32768u : 0u;
  bits16[t] = (unsigned short)m;
}

// One tile step: prefetch (t+1) into KN/VN/WN, compute tile t from KC/WC and
// V buffer at ROFF, then stage V(t+1) into buffer at WOFF. One barrier/tile.
#define STEP(T, KC, KN, VN0, VN1, WC, WN, ROFF, WOFF)                           \
  {                                                                             \
    __syncthreads(); /* V buffer at ROFF now visible; prev reads done */        \
    const bool pfok = (T) + 1 < NT;                                             \
    if (pfok) {                                                                 \
      sptr += 64 * FDIM;                                                        \
      VN0 = *reinterpret_cast<const uint2*>(sptr);                              \
      VN1 = *reinterpret_cast<const uint2*>(sptr + FDIM);                       \
      WN = brow[bcol0 + (T) + 1];                                               \
      kptr += 64 * FDIM;                                                        \
      _Pragma("unroll") for (int t4 = 0; t4 < 4; ++t4)                          \
          KN[t4] = *reinterpret_cast<const uint4*>(kptr + t4 * 16 * FDIM);      \
    }                                                                           \
    f32x4 sc[4];                                                                \
    _Pragma("unroll") for (int t4 = 0; t4 < 4; ++t4) {                          \
      bf16x8 kf = __builtin_bit_cast(bf16x8, KC[t4]);                           \
      sc[t4] = __builtin_amdgcn_mfma_f32_16x16x32_bf16(kf, qf, zf, 0, 0, 0);    \
    }                                                                           \
    const unsigned long long wsh = (WC) >> (4 * g);                             \
    const unsigned mwl = (unsigned)wsh, mwh = (unsigned)(wsh >> 32);            \
    float pf[4][4];                                                             \
    _Pragma("unroll") for (int t4 = 0; t4 < 4; ++t4) {                          \
      const unsigned word = (t4 & 2) ? mwh : mwl;                               \
      _Pragma("unroll") for (int r = 0; r < 4; ++r) {                           \
        float v = sc[t4][r];                                                    \
        v = fmaxf(v, 0.2f * v);                                                 \
        float e = __builtin_amdgcn_exp2f(v);                                    \
        const int pos = 16 * (t4 & 1) + r;                                      \
        const unsigned msk = (unsigned)((int)(word << (31 - pos)) >> 31);       \
        pf[t4][r] =                                                             \
            __builtin_bit_cast(float, __builtin_bit_cast(unsigned, e) & msk);   \
      }                                                                         \
    }                                                                           \
    _Pragma("unroll") for (int u = 0; u < 2; ++u) {                             \
      bf16x8 pa;                                                                \
      _Pragma("unroll") for (int tp = 0; tp < 2; ++tp)                          \
          _Pragma("unroll") for (int r = 0; r < 4; ++r)                         \
              pa[tp * 4 + r] = (__bf16)pf[2 * u + tp][r];                       \
      bf16x8 vf0 = __builtin_bit_cast(bf16x8,                                   \
          *reinterpret_cast<const uint4*>(&Vp[(ROFF) + ql * VCOL + u * 32 + g * 8]));        \
      bf16x8 vf1 = __builtin_bit_cast(bf16x8,                                   \
          *reinterpret_cast<const uint4*>(&Vp[(ROFF) + (16 + ql) * VCOL + u * 32 + g * 8])); \
      acc0 = __builtin_amdgcn_mfma_f32_16x16x32_bf16(pa, vf0, acc0, 0, 0, 0);   \
      acc1 = __builtin_amdgcn_mfma_f32_16x16x32_bf16(pa, vf1, acc1, 0, 0, 0);   \
      accL = __builtin_amdgcn_mfma_f32_16x16x32_bf16(pa, ones, accL, 0, 0, 0);  \
    }                                                                           \
    if (pfok) {                                                                 \
      unsigned* vw = reinterpret_cast<unsigned*>(Vp + (WOFF)) + pi0h;           \
      vw[(4 * c4 + 0) * 36] = __builtin_amdgcn_perm(VN1.x, VN0.x, selA);        \
      vw[(4 * c4 + 1) * 36] = __builtin_amdgcn_perm(VN1.x, VN0.x, selB);        \
      vw[(4 * c4 + 2) * 36] = __builtin_amdgcn_perm(VN1.y, VN0.y, selA);        \
      vw[(4 * c4 + 3) * 36] = __builtin_amdgcn_perm(VN1.y, VN0.y, selB);        \
    }                                                                           \
  }

// ---- main fused attention kernel ----
// Grid: (SEQ/64, NB*NH, NSPLIT). 4 waves/block, each wave owns 16 q-rows.
// K fragments come straight from global (L2-resident) - no K LDS at all.
// V double-buffered in LDS -> one barrier per tile. Static-max softmax.
template <int NSPLIT>
__global__ __launch_bounds__(256, 4) void gat_kernel(
    const unsigned short* __restrict__ xbf,
    const unsigned long long* __restrict__ bits,
    float* __restrict__ dst,     // NSPLIT==1: final out ; else: Opart
    float* __restrict__ lbuf) {  // NSPLIT>1 only: [split][row] = l
  __shared__ __align__(16) unsigned short Vp[2 * VHALF];  // 9216 B

  const int bh = blockIdx.y;
  const int b = bh >> 2;
  const int h = bh & 3;
  const int tid = threadIdx.x;
  const int wid = tid >> 6;
  const int lane = tid & 63;
  const int g = lane >> 4;
  const int ql = lane & 15;
  const int qw = blockIdx.x * 64 + wid * 16;
  const int jbase = blockIdx.z * (SEQ / NSPLIT);
  const int NT = (SEQ / NSPLIT) / 64;

  const unsigned short* xb = xbf + ((size_t)b * SEQ) * FDIM + h * HD;

  // Q fragment, pre-scaled by log2(e) so exp(x) == exp2(score)
  bf16x8 qraw = __builtin_bit_cast(bf16x8,
      *reinterpret_cast<const uint4*>(xb + (size_t)(qw + ql) * FDIM + g * 8));
  bf16x8 qf;
#pragma unroll
  for (int e = 0; e < 8; ++e) qf[e] = (__bf16)((float)qraw[e] * LOG2E);

  bf16x8 ones;
#pragma unroll
  for (int e = 0; e < 8; ++e) ones[e] = (__bf16)1.0f;
  const f32x4 zf = {0.f, 0.f, 0.f, 0.f};

  f32x4 acc0 = {0.f, 0.f, 0.f, 0.f};  // O[row=4g+r][col=ql]
  f32x4 acc1 = {0.f, 0.f, 0.f, 0.f};  // O[row=4g+r][col=16+ql]
  f32x4 accL = {0.f, 0.f, 0.f, 0.f};  // l[row=4g+r]

  const unsigned long long* brow = bits + (size_t)(qw + ql) * (SEQ / 64);
  const int bcol0 = jbase >> 6;

  // K fragment source: row jbase+16*t4+ql, cols g*8..g*8+7 (advance 64 rows/tile)
  const unsigned short* kptr = xb + (size_t)(jbase + ql) * FDIM + g * 8;

  // V staging map: thread -> rows (2*pr, 2*pr+1), cols 4*c4..4*c4+3
  const int pr = tid >> 3;  // 0..31
  const int c4 = tid & 7;   // 0..7
  const unsigned short* sptr = xb + (size_t)(jbase + 2 * pr) * FDIM + c4 * 4;

  // pi(j): j=[u|tp|g|r] (bits 5|4|3:2|1:0) -> [u|g|tp|r]; pi0h = pi(2pr)/2
  const int pi0h =
      (32 * (pr >> 4) + 8 * ((pr >> 1) & 3) + 4 * ((pr >> 3) & 1) + 2 * (pr & 1)) >> 1;

  const unsigned selA = 0x05040100u;  // [lo.b0, lo.b1, hi.b0, hi.b1]
  const unsigned selB = 0x07060302u;  // [lo.b2, lo.b3, hi.b2, hi.b3]

  // prologue: tile 0 -> ka/va/wa, stage V buffer 0
  uint4 ka[4], kb[4];
  uint2 va0, va1, vb0, vb1;
  unsigned long long wa, wb;
#pragma unroll
  for (int t4 = 0; t4 < 4; ++t4)
    ka[t4] = *reinterpret_cast<const uint4*>(kptr + t4 * 16 * FDIM);
  va0 = *reinterpret_cast<const uint2*>(sptr);
  va1 = *reinterpret_cast<const uint2*>(sptr + FDIM);
  wa = brow[bcol0];
  {
    unsigned* vw = reinterpret_cast<unsigned*>(Vp) + pi0h;
    vw[(4 * c4 + 0) * 36] = __builtin_amdgcn_perm(va1.x, va0.x, selA);
    vw[(4 * c4 + 1) * 36] = __builtin_amdgcn_perm(va1.x, va0.x, selB);
    vw[(4 * c4 + 2) * 36] = __builtin_amdgcn_perm(va1.y, va0.y, selA);
    vw[(4 * c4 + 3) * 36] = __builtin_amdgcn_perm(va1.y, va0.y, selB);
  }

  for (int t = 0; t < NT; t += 2) {
    STEP(t, ka, kb, vb0, vb1, wa, wb, 0, VHALF);
    STEP(t + 1, kb, ka, va0, va1, wb, wa, VHALF, 0);
  }

  if (NSPLIT == 1) {
#pragma unroll
    for (int r = 0; r < 4; ++r) {
      const float inv = 1.f / accL[r];
      const size_t o = ((size_t)b * SEQ + (size_t)(qw + 4 * g + r)) * FDIM + h * HD;
      dst[o + ql] = acc0[r] * inv;
      dst[o + 16 + ql] = acc1[r] * inv;
    }
  } else {
    float* Op = dst + (((size_t)blockIdx.z * (NB * NH) + bh) * SEQ) * HD;
#pragma unroll
    for (int r = 0; r < 4; ++r) {
      const int q = qw + 4 * g + r;
      Op[(size_t)q * HD + ql] = acc0[r];
      Op[(size_t)q * HD + 16 + ql] = acc1[r];
    }
    if (ql == 0) {
#pragma unroll
      for (int r = 0; r < 4; ++r)
        lbuf[(size_t)blockIdx.z * NROWS + (size_t)bh * SEQ + qw + 4 * g + r] = accL[r];
    }
  }
}

// ---- combine partials (split path): out = sum(O_s) / sum(l_s) ----
template <int NSPLIT>
__global__ __launch_bounds__(256) void combine_kernel(
    const float* __restrict__ Op, const float* __restrict__ lbuf, float* __restrict__ out) {
  const int idx = blockIdx.x * 256 + threadIdx.x;  // unit: 4 floats
  const int row = idx >> 3;
  const int dc = (idx & 7) * 4;
  float lt = 0.f;
  float4 o = {0.f, 0.f, 0.f, 0.f};
#pragma unroll
  for (int s = 0; s < NSPLIT; ++s) {
    lt += lbuf[(size_t)s * NROWS + row];
    float4 v = *reinterpret_cast<const float4*>(Op + ((size_t)s * NROWS + row) * HD + dc);
    o.x += v.x; o.y += v.y; o.z += v.z; o.w += v.w;
  }
  const float inv = 1.f / lt;
  const int bh = row >> 12;
  const int q = row & (SEQ - 1);
  const int b = bh >> 2;
  const int h = bh & 3;
  float4 w;
  w.x = o.x * inv; w.y = o.y * inv; w.z = o.z * inv; w.w = o.w * inv;
  *reinterpret_cast<float4*>(out + ((size_t)b * SEQ + q) * FDIM + h * HD + dc) = w;
}

extern "C" void kernel_launch(void* const* d_in, const int* in_sizes, int n_in,
                              void* d_out, int out_size, void* d_ws, size_t ws_size,
                              hipStream_t stream) {
  (void)in_sizes; (void)n_in; (void)out_size;
  const float* x = (const float*)d_in[0];
  const int* adj = (const int*)d_in[1];
  float* outp = (float*)d_out;

  unsigned short* xbf = (unsigned short*)d_ws;                           // 2 MiB
  unsigned short* bits16 = (unsigned short*)((char*)d_ws + (2u << 20));  // 2 MiB
  float* Opart = (float*)((char*)d_ws + (4u << 20));
  auto need = [](int s) {
    return (size_t)(4u << 20) + (size_t)s * NROWS * HD * 4 + (size_t)s * NROWS * 4;
  };

  cvt_kernel<<<(NB * SEQ * FDIM) / (256 * 4), 256, 0, stream>>>(x, xbf);
  adjpack_kernel<<<(SEQ * SEQ) / (16 * 256), 256, 0, stream>>>(adj, bits16);

  const unsigned long long* bits = (const unsigned long long*)bits16;
  if (ws_size >= need(4)) {
    float* mlb = (float*)((char*)d_ws + (4u << 20) + (size_t)4 * NROWS * HD * 4);
    dim3 grid(SEQ / 64, NB * NH, 4);
    gat_kernel<4><<<grid, 256, 0, stream>>>(xbf, bits, Opart, mlb);
    combine_kernel<4><<<(NROWS * 8) / 256, 256, 0, stream>>>(Opart, mlb, outp);
  } else if (ws_size >= need(2)) {
    float* mlb = (float*)((char*)d_ws + (4u << 20) + (size_t)2 * NROWS * HD * 4);
    dim3 grid(SEQ / 64, NB * NH, 2);
    gat_kernel<2><<<grid, 256, 0, stream>>>(xbf, bits, Opart, mlb);
    combine_kernel<2><<<(NROWS * 8) / 256, 256, 0, stream>>>(Opart, mlb, outp);
  } else {
    dim3 grid(SEQ / 64, NB * NH, 1);
    gat_kernel<1><<<grid, 256, 0, stream>>>(xbf, bits, outp, nullptr);
  }
}

// Round 6
// 70.809 us; speedup vs baseline: 1.5650x; 1.5650x over previous
//
#include <hip/hip_runtime.h>
#include <stdint.h>

#define SEQ 4096
#define FDIM 128
#define NH 4
#define HD 32
#define NB 2
#define NROWS (NB * NH * SEQ)  // 32768
#define LOG2E 1.4426950408889634f
#define VCOL 72            // shorts per Vp column (36 dwords)
#define VHALF (32 * VCOL)  // shorts per Vp buffer (4608 B)

typedef float f32x4 __attribute__((ext_vector_type(4)));
typedef __bf16 bf16x8 __attribute__((ext_vector_type(8)));

__device__ __forceinline__ unsigned short f2bf(float f) {
  unsigned int u = __builtin_bit_cast(unsigned int, f);
  return (unsigned short)((u + 0x7FFFu + ((u >> 16) & 1u)) >> 16);  // RTNE
}

// ---- pre-pass 1: fp32 -> bf16 ----
__global__ void cvt_kernel(const float* __restrict__ in, unsigned short* __restrict__ out) {
  int i = (blockIdx.x * 256 + threadIdx.x) * 4;
  float4 v = *reinterpret_cast<const float4*>(in + i);
  ushort4 o;
  o.x = f2bf(v.x); o.y = f2bf(v.y); o.z = f2bf(v.z); o.w = f2bf(v.w);
  *reinterpret_cast<ushort4*>(out + i) = o;
}

// ---- pre-pass 2: adjacency int32 -> bitmask; 16 ints/thread ----
__global__ void adjpack_kernel(const int* __restrict__ adj, unsigned short* __restrict__ bits16) {
  size_t t = (size_t)blockIdx.x * 256 + threadIdx.x;
  const uint4* p = reinterpret_cast<const uint4*>(adj) + t * 4;
  uint4 a = p[0], b = p[1], c = p[2], d = p[3];
  unsigned m = 0;
  m |= (a.x != 0) ? 1u : 0u;        m |= (a.y != 0) ? 2u : 0u;
  m |= (a.z != 0) ? 4u : 0u;        m |= (a.w != 0) ? 8u : 0u;
  m |= (b.x != 0) ? 16u : 0u;       m |= (b.y != 0) ? 32u : 0u;
  m |= (b.z != 0) ? 64u : 0u;       m |= (b.w != 0) ? 128u : 0u;
  m |= (c.x != 0) ? 256u : 0u;      m |= (c.y != 0) ? 512u : 0u;
  m |= (c.z != 0) ? 1024u : 0u;     m |= (c.w != 0) ? 2048u : 0u;
  m |= (d.x != 0) ? 4096u : 0u;     m |= (d.y != 0) ? 8192u : 0u;
  m |= (d.z != 0) ? 16384u : 0u;    m |= (d.w != 0) ? 32768u : 0u;
  bits16[t] = (unsigned short)m;
}

// One tile step, single barrier. RB = read buffer index, WBUF = write buffer.
// Top barrier makes buffer RB (written at end of previous step) visible AND
// guarantees everyone is done reading buffer WBUF from two steps ago.
#define STEP(T, RB, WBUF)                                                       \
  {                                                                             \
    __syncthreads();                                                            \
    const bool pfok = (T) + 1 < NT;                                             \
    if (pfok) { /* prefetch tile T+1 staging data (consumed at step end) */     \
      sptr += 64 * FDIM;                                                        \
      r0 = *reinterpret_cast<const uint2*>(sptr);                               \
      r1 = *reinterpret_cast<const uint2*>(sptr + FDIM);                        \
      wnext = brow[bcol0 + (T) + 1];                                            \
    }                                                                           \
    f32x4 sc[4];                                                                \
    __builtin_amdgcn_s_setprio(1);                                              \
    _Pragma("unroll") for (int t4 = 0; t4 < 4; ++t4) {                          \
      bf16x8 kf = __builtin_bit_cast(bf16x8,                                    \
          *reinterpret_cast<const uint4*>(&Kl[RB][t4 * 16 + ql][g * 8]));       \
      sc[t4] = __builtin_amdgcn_mfma_f32_16x16x32_bf16(kf, qf, zf, 0, 0, 0);    \
    }                                                                           \
    __builtin_amdgcn_s_setprio(0);                                              \
    const unsigned long long wsh = wcur >> (4 * g);                             \
    const unsigned mwl = (unsigned)wsh, mwh = (unsigned)(wsh >> 32);            \
    float pf4[4][4];                                                            \
    _Pragma("unroll") for (int t4 = 0; t4 < 4; ++t4) {                          \
      const unsigned word = (t4 & 2) ? mwh : mwl;                               \
      _Pragma("unroll") for (int r = 0; r < 4; ++r) {                           \
        float v = sc[t4][r];                                                    \
        v = fmaxf(v, 0.2f * v);                       /* leaky_relu */          \
        float e = __builtin_amdgcn_exp2f(v);          /* unshifted exp2 */      \
        const int pos = 16 * (t4 & 1) + r;                                      \
        const unsigned msk = (unsigned)((int)(word << (31 - pos)) >> 31);       \
        pf4[t4][r] =                                                            \
            __builtin_bit_cast(float, __builtin_bit_cast(unsigned, e) & msk);   \
      }                                                                         \
    }                                                                           \
    __builtin_amdgcn_s_setprio(1);                                              \
    _Pragma("unroll") for (int u = 0; u < 2; ++u) {                             \
      bf16x8 pa;                                                                \
      _Pragma("unroll") for (int tp = 0; tp < 2; ++tp)                          \
          _Pragma("unroll") for (int r = 0; r < 4; ++r)                         \
              pa[tp * 4 + r] = (__bf16)pf4[2 * u + tp][r];                      \
      bf16x8 vf0 = __builtin_bit_cast(bf16x8,                                   \
          *reinterpret_cast<const uint4*>(&Vp[RB][ql * VCOL + u * 32 + g * 8]));        \
      bf16x8 vf1 = __builtin_bit_cast(bf16x8,                                   \
          *reinterpret_cast<const uint4*>(&Vp[RB][(16 + ql) * VCOL + u * 32 + g * 8])); \
      acc0 = __builtin_amdgcn_mfma_f32_16x16x32_bf16(pa, vf0, acc0, 0, 0, 0);   \
      acc1 = __builtin_amdgcn_mfma_f32_16x16x32_bf16(pa, vf1, acc1, 0, 0, 0);   \
      accL = __builtin_amdgcn_mfma_f32_16x16x32_bf16(pa, ones, accL, 0, 0, 0);  \
    }                                                                           \
    __builtin_amdgcn_s_setprio(0);                                              \
    if (pfok) { /* stage tile T+1 into the other buffer (no barrier needed) */  \
      *reinterpret_cast<uint2*>(&Kl[WBUF][2 * pr][c4 * 4]) = r0;                \
      *reinterpret_cast<uint2*>(&Kl[WBUF][2 * pr + 1][c4 * 4]) = r1;            \
      unsigned* vw = reinterpret_cast<unsigned*>(&Vp[WBUF][0]) + pi0h;          \
      vw[(4 * c4 + 0) * 36] = __builtin_amdgcn_perm(r1.x, r0.x, selA);          \
      vw[(4 * c4 + 1) * 36] = __builtin_amdgcn_perm(r1.x, r0.x, selB);          \
      vw[(4 * c4 + 2) * 36] = __builtin_amdgcn_perm(r1.y, r0.y, selA);          \
      vw[(4 * c4 + 3) * 36] = __builtin_amdgcn_perm(r1.y, r0.y, selB);          \
    }                                                                           \
    wcur = wnext;                                                               \
  }

// ---- main fused attention kernel ----
// Grid: (SEQ/64, NB*NH, NSPLIT). 4 waves/block, each wave owns 16 q-rows.
// K row-major + V pi-col-major both double-buffered in LDS; one barrier/tile.
// Static-max softmax; l via ones-MFMA; sbfe-AND mask.
template <int NSPLIT>
__global__ __launch_bounds__(256, 4) void gat_kernel(
    const unsigned short* __restrict__ xbf,
    const unsigned long long* __restrict__ bits,
    float* __restrict__ dst,     // NSPLIT==1: final out ; else: Opart
    float* __restrict__ lbuf) {  // NSPLIT>1 only: [split][row] = l
  __shared__ __align__(16) unsigned short Kl[2][64][40];  // 2 x 5120 B
  __shared__ __align__(16) unsigned short Vp[2][VHALF];   // 2 x 4608 B

  const int bh = blockIdx.y;
  const int b = bh >> 2;
  const int h = bh & 3;
  const int tid = threadIdx.x;
  const int wid = tid >> 6;
  const int lane = tid & 63;
  const int g = lane >> 4;
  const int ql = lane & 15;
  const int qw = blockIdx.x * 64 + wid * 16;
  const int jbase = blockIdx.z * (SEQ / NSPLIT);
  const int NT = (SEQ / NSPLIT) / 64;

  const unsigned short* xb = xbf + ((size_t)b * SEQ) * FDIM + h * HD;

  // Q fragment, pre-scaled by log2(e) so exp(x) == exp2(score)
  bf16x8 qraw = __builtin_bit_cast(bf16x8,
      *reinterpret_cast<const uint4*>(xb + (size_t)(qw + ql) * FDIM + g * 8));
  bf16x8 qf;
#pragma unroll
  for (int e = 0; e < 8; ++e) qf[e] = (__bf16)((float)qraw[e] * LOG2E);

  bf16x8 ones;
#pragma unroll
  for (int e = 0; e < 8; ++e) ones[e] = (__bf16)1.0f;
  const f32x4 zf = {0.f, 0.f, 0.f, 0.f};

  f32x4 acc0 = {0.f, 0.f, 0.f, 0.f};  // O[row=4g+r][col=ql]
  f32x4 acc1 = {0.f, 0.f, 0.f, 0.f};  // O[row=4g+r][col=16+ql]
  f32x4 accL = {0.f, 0.f, 0.f, 0.f};  // l[row=4g+r]

  const unsigned long long* brow = bits + (size_t)(qw + ql) * (SEQ / 64);
  const int bcol0 = jbase >> 6;

  // staging map: thread -> rows (2*pr, 2*pr+1), cols 4*c4..4*c4+3
  const int pr = tid >> 3;  // 0..31
  const int c4 = tid & 7;   // 0..7
  const unsigned short* sptr = xb + (size_t)(jbase + 2 * pr) * FDIM + c4 * 4;

  // pi(j): j=[u|tp|g|r] (bits 5|4|3:2|1:0) -> [u|g|tp|r]; pi0h = pi(2pr)/2
  const int pi0h =
      (32 * (pr >> 4) + 8 * ((pr >> 1) & 3) + 4 * ((pr >> 3) & 1) + 2 * (pr & 1)) >> 1;

  const unsigned selA = 0x05040100u;  // [lo.b0, lo.b1, hi.b0, hi.b1]
  const unsigned selB = 0x07060302u;  // [lo.b2, lo.b3, hi.b2, hi.b3]

  // prologue: load + stage tile 0 into buffer 0
  uint2 r0 = *reinterpret_cast<const uint2*>(sptr);
  uint2 r1 = *reinterpret_cast<const uint2*>(sptr + FDIM);
  unsigned long long wcur = brow[bcol0];
  unsigned long long wnext = 0;
  *reinterpret_cast<uint2*>(&Kl[0][2 * pr][c4 * 4]) = r0;
  *reinterpret_cast<uint2*>(&Kl[0][2 * pr + 1][c4 * 4]) = r1;
  {
    unsigned* vw = reinterpret_cast<unsigned*>(&Vp[0][0]) + pi0h;
    vw[(4 * c4 + 0) * 36] = __builtin_amdgcn_perm(r1.x, r0.x, selA);
    vw[(4 * c4 + 1) * 36] = __builtin_amdgcn_perm(r1.x, r0.x, selB);
    vw[(4 * c4 + 2) * 36] = __builtin_amdgcn_perm(r1.y, r0.y, selA);
    vw[(4 * c4 + 3) * 36] = __builtin_amdgcn_perm(r1.y, r0.y, selB);
  }

  for (int t = 0; t < NT; t += 2) {
    STEP(t, 0, 1);
    STEP(t + 1, 1, 0);
  }

  if (NSPLIT == 1) {
#pragma unroll
    for (int r = 0; r < 4; ++r) {
      const float inv = 1.f / accL[r];
      const size_t o = ((size_t)b * SEQ + (size_t)(qw + 4 * g + r)) * FDIM + h * HD;
      dst[o + ql] = acc0[r] * inv;
      dst[o + 16 + ql] = acc1[r] * inv;
    }
  } else {
    float* Op = dst + (((size_t)blockIdx.z * (NB * NH) + bh) * SEQ) * HD;
#pragma unroll
    for (int r = 0; r < 4; ++r) {
      const int q = qw + 4 * g + r;
      Op[(size_t)q * HD + ql] = acc0[r];
      Op[(size_t)q * HD + 16 + ql] = acc1[r];
    }
    if (ql == 0) {
#pragma unroll
      for (int r = 0; r < 4; ++r)
        lbuf[(size_t)blockIdx.z * NROWS + (size_t)bh * SEQ + qw + 4 * g + r] = accL[r];
    }
  }
}

// ---- combine partials (split path): out = sum(O_s) / sum(l_s) ----
template <int NSPLIT>
__global__ __launch_bounds__(256) void combine_kernel(
    const float* __restrict__ Op, const float* __restrict__ lbuf, float* __restrict__ out) {
  const int idx = blockIdx.x * 256 + threadIdx.x;  // unit: 4 floats
  const int row = idx >> 3;
  const int dc = (idx & 7) * 4;
  float lt = 0.f;
  float4 o = {0.f, 0.f, 0.f, 0.f};
#pragma unroll
  for (int s = 0; s < NSPLIT; ++s) {
    lt += lbuf[(size_t)s * NROWS + row];
    float4 v = *reinterpret_cast<const float4*>(Op + ((size_t)s * NROWS + row) * HD + dc);
    o.x += v.x; o.y += v.y; o.z += v.z; o.w += v.w;
  }
  const float inv = 1.f / lt;
  const int bh = row >> 12;
  const int q = row & (SEQ - 1);
  const int b = bh >> 2;
  const int h = bh & 3;
  float4 w;
  w.x = o.x * inv; w.y = o.y * inv; w.z = o.z * inv; w.w = o.w * inv;
  *reinterpret_cast<float4*>(out + ((size_t)b * SEQ + q) * FDIM + h * HD + dc) = w;
}

extern "C" void kernel_launch(void* const* d_in, const int* in_sizes, int n_in,
                              void* d_out, int out_size, void* d_ws, size_t ws_size,
                              hipStream_t stream) {
  (void)in_sizes; (void)n_in; (void)out_size;
  const float* x = (const float*)d_in[0];
  const int* adj = (const int*)d_in[1];
  float* outp = (float*)d_out;

  unsigned short* xbf = (unsigned short*)d_ws;                           // 2 MiB
  unsigned short* bits16 = (unsigned short*)((char*)d_ws + (2u << 20));  // 2 MiB
  float* Opart = (float*)((char*)d_ws + (4u << 20));
  auto need = [](int s) {
    return (size_t)(4u << 20) + (size_t)s * NROWS * HD * 4 + (size_t)s * NROWS * 4;
  };

  cvt_kernel<<<(NB * SEQ * FDIM) / (256 * 4), 256, 0, stream>>>(x, xbf);
  adjpack_kernel<<<(SEQ * SEQ) / (16 * 256), 256, 0, stream>>>(adj, bits16);

  const unsigned long long* bits = (const unsigned long long*)bits16;
  if (ws_size >= need(4)) {
    float* mlb = (float*)((char*)d_ws + (4u << 20) + (size_t)4 * NROWS * HD * 4);
    dim3 grid(SEQ / 64, NB * NH, 4);
    gat_kernel<4><<<grid, 256, 0, stream>>>(xbf, bits, Opart, mlb);
    combine_kernel<4><<<(NROWS * 8) / 256, 256, 0, stream>>>(Opart, mlb, outp);
  } else if (ws_size >= need(2)) {
    float* mlb = (float*)((char*)d_ws + (4u << 20) + (size_t)2 * NROWS * HD * 4);
    dim3 grid(SEQ / 64, NB * NH, 2);
    gat_kernel<2><<<grid, 256, 0, stream>>>(xbf, bits, Opart, mlb);
    combine_kernel<2><<<(NROWS * 8) / 256, 256, 0, stream>>>(Opart, mlb, outp);
  } else {
    dim3 grid(SEQ / 64, NB * NH, 1);
    gat_kernel<1><<<grid, 256, 0, stream>>>(xbf, bits, outp, nullptr);
  }
}